// Round 1
// baseline (352.787 us; speedup 1.0000x reference)
//
#include <hip/hip_runtime.h>
#include <hip/hip_bf16.h>

#define SEQ 2048
#define SCALE 0.125f
#define LOG2E 1.4426950408889634f

typedef __bf16 bf16;
typedef __bf16 bf16x4 __attribute__((ext_vector_type(4)));
typedef __bf16 bf16x8 __attribute__((ext_vector_type(8)));
typedef float f32x4 __attribute__((ext_vector_type(4)));
typedef unsigned int u32;

__device__ __forceinline__ void gl_lds16(const void* g, void* l) {
    __builtin_amdgcn_global_load_lds((const __attribute__((address_space(1))) u32*)g,
                                     (__attribute__((address_space(3))) u32*)l, 16, 0, 0);
}

// ---------------- prep kernels ----------------

__global__ __launch_bounds__(256) void k_cast_x(const float4* __restrict__ x,
                                                bf16x4* __restrict__ xb) {
    int t = blockIdx.x * 256 + threadIdx.x;
    float4 f = x[t];
    bf16x4 o;
    o[0] = (bf16)f.x; o[1] = (bf16)f.y; o[2] = (bf16)f.z; o[3] = (bf16)f.w;
    xb[t] = o;
}

// src [1024][1024] fp32 -> dst [1024][1024] bf16 transposed: dst[c][r] = src[r][c]
__global__ __launch_bounds__(256) void k_transpose_cast(const float* __restrict__ src,
                                                        bf16* __restrict__ dst) {
    __shared__ float tile[32][33];
    int bx = blockIdx.x * 32;   // src col base
    int by = blockIdx.y * 32;   // src row base
    int tx = threadIdx.x;       // 0..31
    int ty = threadIdx.y;       // 0..7
#pragma unroll
    for (int j = 0; j < 32; j += 8)
        tile[ty + j][tx] = src[(size_t)(by + ty + j) * 1024 + bx + tx];
    __syncthreads();
#pragma unroll
    for (int j = 0; j < 32; j += 8)
        dst[(size_t)(bx + ty + j) * 1024 + by + tx] = (bf16)tile[tx][ty + j];
}

// ---------------- GEMM 1: QV = Xb @ [Wq|Wv] + bias, scatter epilogue ----------------
// A = Xb [8192][1024] bf16, B = Wqvt [2048][1024] bf16 (row n = col n of Wq / Wv)
// C(m,n): n<1024 -> Q[bh][s][dh], n>=1024 -> Vt[bh][dh][s]; also QN[bh][s] = ||q_row||^2

__global__ __launch_bounds__(256) void k_gemm_qv(const bf16* __restrict__ Xb,
                                                 const bf16* __restrict__ Wqvt,
                                                 const float* __restrict__ bq,
                                                 const float* __restrict__ bv,
                                                 bf16* __restrict__ Q,
                                                 bf16* __restrict__ Vt,
                                                 float* __restrict__ QN) {
    constexpr int K = 1024;
    __shared__ bf16 As[128 * 32];
    __shared__ bf16 Bs[128 * 32];
    int t = threadIdx.x, w = t >> 6, l = t & 63;
    int blockN = blockIdx.x * 128, blockM = blockIdx.y * 128;
    int wm = w & 1, wn = w >> 1;
    int lr = l & 15, quad = l >> 4, q8 = quad * 8;
    int skcol = (l & 3) * 8;

    f32x4 acc[4][4] = {};
    const bf16* Ab = Xb + (size_t)blockM * K;
    const bf16* Bb = Wqvt + (size_t)blockN * K;

    for (int k0 = 0; k0 < K; k0 += 32) {
#pragma unroll
        for (int c2 = 0; c2 < 2; ++c2) {
            int c = 2 * w + c2;
            int row = c * 16 + (l >> 2);
            gl_lds16(Ab + (size_t)row * K + k0 + skcol, As + c * 512);
            gl_lds16(Bb + (size_t)row * K + k0 + skcol, Bs + c * 512);
        }
        __syncthreads();
        const bf16* Aw = As + wm * 64 * 32;
        const bf16* Bw = Bs + wn * 64 * 32;
        bf16x8 af[4], bfr[4];
#pragma unroll
        for (int mi = 0; mi < 4; ++mi) af[mi] = *(const bf16x8*)(Aw + (mi * 16 + lr) * 32 + q8);
#pragma unroll
        for (int ni = 0; ni < 4; ++ni) bfr[ni] = *(const bf16x8*)(Bw + (ni * 16 + lr) * 32 + q8);
#pragma unroll
        for (int mi = 0; mi < 4; ++mi)
#pragma unroll
            for (int ni = 0; ni < 4; ++ni)
                acc[mi][ni] = __builtin_amdgcn_mfma_f32_16x16x32_bf16(af[mi], bfr[ni], acc[mi][ni], 0, 0, 0);
        __syncthreads();
    }

    // epilogue
    int colbase = blockN + wn * 64;          // multiple of 64 -> one head per wave
    bool isQ = colbase < 1024;
    int h = ((isQ ? colbase : colbase - 1024) >> 6);
    float bias[4];
#pragma unroll
    for (int ni = 0; ni < 4; ++ni) {
        int col = colbase + ni * 16 + lr;
        bias[ni] = isQ ? bq[col] : bv[col - 1024];
    }
#pragma unroll
    for (int mi = 0; mi < 4; ++mi) {
#pragma unroll
        for (int r = 0; r < 4; ++r) {
            int m = blockM + wm * 64 + mi * 16 + quad * 4 + r;
            int b = m >> 11, s = m & 2047;
            int bh = (b << 4) + h;
            float qsq = 0.f;
#pragma unroll
            for (int ni = 0; ni < 4; ++ni) {
                float v = acc[mi][ni][r] + bias[ni];
                bf16 vb = (bf16)v;
                int dh = ni * 16 + lr;
                if (isQ) {
                    Q[((size_t)bh * SEQ + s) * 64 + dh] = vb;
                    float vr = (float)vb;
                    qsq += vr * vr;
                } else {
                    Vt[((size_t)bh * 64 + dh) * SEQ + s] = vb;
                }
            }
            if (isQ) {
                qsq += __shfl_xor(qsq, 1);
                qsq += __shfl_xor(qsq, 2);
                qsq += __shfl_xor(qsq, 4);
                qsq += __shfl_xor(qsq, 8);
                if (lr == 0) QN[(size_t)bh * SEQ + s] = qsq;
            }
        }
    }
}

// ---------------- attention: flash-style, no max tracking ----------------
// grid: x = 32 (i-tiles of 64 rows), y = 64 (b*h). 256 threads = 4 waves x 16 rows.

__global__ __launch_bounds__(256) void k_attn(const bf16* __restrict__ Q,
                                              const bf16* __restrict__ Vt,
                                              const float* __restrict__ QN,
                                              bf16* __restrict__ AO) {
    constexpr int LDP = 72;  // padded stride (bank-conflict-free, 16B aligned)
    __shared__ bf16 Qs[64 * LDP];
    __shared__ bf16 Ks[64 * LDP];
    __shared__ bf16 Vts[64 * LDP];
    __shared__ bf16 Ps[4][16 * LDP];

    int t = threadIdx.x, w = t >> 6, l = t & 63;
    int bh = blockIdx.y;
    int i0 = blockIdx.x * 64;
    const bf16* Qh = Q + (size_t)bh * SEQ * 64;
    const bf16* Vh = Vt + (size_t)bh * 64 * SEQ;
    const float* BBh = QN + (size_t)bh * SEQ;
    int lr = l & 15, quad = l >> 4, q8 = quad * 8;

    // stage Q rows [i0, i0+64)
    for (int ch = t; ch < 512; ch += 256) {
        int row = ch >> 3, c8 = (ch & 7) * 8;
        *(bf16x8*)(Qs + row * LDP + c8) = *(const bf16x8*)(Qh + (size_t)(i0 + row) * 64 + c8);
    }
    __syncthreads();
    bf16x8 af[2];
    af[0] = *(const bf16x8*)(Qs + (w * 16 + lr) * LDP + q8);
    af[1] = *(const bf16x8*)(Qs + (w * 16 + lr) * LDP + 32 + q8);

    f32x4 oacc[4] = {};
    float dpart[4] = {0.f, 0.f, 0.f, 0.f};

    for (int j0 = 0; j0 < SEQ; j0 += 64) {
        __syncthreads();
        for (int ch = t; ch < 512; ch += 256) {
            int row = ch >> 3, c8 = (ch & 7) * 8;
            *(bf16x8*)(Ks + row * LDP + c8) = *(const bf16x8*)(Qh + (size_t)(j0 + row) * 64 + c8);
            *(bf16x8*)(Vts + row * LDP + c8) = *(const bf16x8*)(Vh + (size_t)row * SEQ + j0 + c8);
        }
        __syncthreads();

        // S = q_i . q_j  (16 rows x 64 cols per wave)
        f32x4 sacc[4] = {};
#pragma unroll
        for (int ni = 0; ni < 4; ++ni) {
            bf16x8 b0 = *(const bf16x8*)(Ks + (ni * 16 + lr) * LDP + q8);
            bf16x8 b1 = *(const bf16x8*)(Ks + (ni * 16 + lr) * LDP + 32 + q8);
            sacc[ni] = __builtin_amdgcn_mfma_f32_16x16x32_bf16(af[0], b0, sacc[ni], 0, 0, 0);
            sacc[ni] = __builtin_amdgcn_mfma_f32_16x16x32_bf16(af[1], b1, sacc[ni], 0, 0, 0);
        }

        // P = exp((2AB - BB) * SCALE); accumulate denominator; write P to LDS (bf16)
#pragma unroll
        for (int ni = 0; ni < 4; ++ni) {
            float bbt = BBh[j0 + ni * 16 + lr] * (SCALE * LOG2E);
#pragma unroll
            for (int r = 0; r < 4; ++r) {
                float p = __builtin_amdgcn_exp2f(sacc[ni][r] * (2.f * SCALE * LOG2E) - bbt);
                dpart[r] += p;
                Ps[w][(quad * 4 + r) * LDP + ni * 16 + lr] = (bf16)p;
            }
        }

        // O += P @ V   (P: A-layout from LDS; Vt rows are B^T form)
#pragma unroll
        for (int kc = 0; kc < 2; ++kc) {
            bf16x8 ap = *(const bf16x8*)(&Ps[w][lr * LDP + kc * 32 + q8]);
#pragma unroll
            for (int di = 0; di < 4; ++di) {
                bf16x8 bv8 = *(const bf16x8*)(Vts + (di * 16 + lr) * LDP + kc * 32 + q8);
                oacc[di] = __builtin_amdgcn_mfma_f32_16x16x32_bf16(ap, bv8, oacc[di], 0, 0, 0);
            }
        }
    }

    // epilogue: divide by denominator, write merged-head layout [b, s, h*64+d]
    int b = bh >> 4, h = bh & 15;
#pragma unroll
    for (int r = 0; r < 4; ++r) {
        float d = dpart[r];
        d += __shfl_xor(d, 1);
        d += __shfl_xor(d, 2);
        d += __shfl_xor(d, 4);
        d += __shfl_xor(d, 8);
        float inv = 1.f / d;
        int s = i0 + w * 16 + quad * 4 + r;
#pragma unroll
        for (int di = 0; di < 4; ++di) {
            AO[((size_t)(b * SEQ + s)) * 1024 + h * 64 + di * 16 + lr] = (bf16)(oacc[di][r] * inv);
        }
    }
}

// ---------------- GEMM 3: out = AO @ Wo + bo ----------------

__global__ __launch_bounds__(256) void k_gemm_out(const bf16* __restrict__ AO,
                                                  const bf16* __restrict__ Wot,
                                                  const float* __restrict__ bo,
                                                  float* __restrict__ out) {
    constexpr int K = 1024;
    __shared__ bf16 As[128 * 32];
    __shared__ bf16 Bs[128 * 32];
    int t = threadIdx.x, w = t >> 6, l = t & 63;
    int blockN = blockIdx.x * 128, blockM = blockIdx.y * 128;
    int wm = w & 1, wn = w >> 1;
    int lr = l & 15, quad = l >> 4, q8 = quad * 8;
    int skcol = (l & 3) * 8;

    f32x4 acc[4][4] = {};
    const bf16* Ab = AO + (size_t)blockM * K;
    const bf16* Bb = Wot + (size_t)blockN * K;

    for (int k0 = 0; k0 < K; k0 += 32) {
#pragma unroll
        for (int c2 = 0; c2 < 2; ++c2) {
            int c = 2 * w + c2;
            int row = c * 16 + (l >> 2);
            gl_lds16(Ab + (size_t)row * K + k0 + skcol, As + c * 512);
            gl_lds16(Bb + (size_t)row * K + k0 + skcol, Bs + c * 512);
        }
        __syncthreads();
        const bf16* Aw = As + wm * 64 * 32;
        const bf16* Bw = Bs + wn * 64 * 32;
        bf16x8 af[4], bfr[4];
#pragma unroll
        for (int mi = 0; mi < 4; ++mi) af[mi] = *(const bf16x8*)(Aw + (mi * 16 + lr) * 32 + q8);
#pragma unroll
        for (int ni = 0; ni < 4; ++ni) bfr[ni] = *(const bf16x8*)(Bw + (ni * 16 + lr) * 32 + q8);
#pragma unroll
        for (int mi = 0; mi < 4; ++mi)
#pragma unroll
            for (int ni = 0; ni < 4; ++ni)
                acc[mi][ni] = __builtin_amdgcn_mfma_f32_16x16x32_bf16(af[mi], bfr[ni], acc[mi][ni], 0, 0, 0);
        __syncthreads();
    }

    int colbase = blockN + wn * 64;
    float bias[4];
#pragma unroll
    for (int ni = 0; ni < 4; ++ni) bias[ni] = bo[colbase + ni * 16 + lr];
#pragma unroll
    for (int mi = 0; mi < 4; ++mi) {
#pragma unroll
        for (int r = 0; r < 4; ++r) {
            int m = blockM + wm * 64 + mi * 16 + quad * 4 + r;
#pragma unroll
            for (int ni = 0; ni < 4; ++ni) {
                out[(size_t)m * 1024 + colbase + ni * 16 + lr] = acc[mi][ni][r] + bias[ni];
            }
        }
    }
}

// ---------------- launch ----------------

extern "C" void kernel_launch(void* const* d_in, const int* in_sizes, int n_in,
                              void* d_out, int out_size, void* d_ws, size_t ws_size,
                              hipStream_t stream) {
    const float* x  = (const float*)d_in[0];
    const float* Wq = (const float*)d_in[1];
    const float* bq = (const float*)d_in[2];
    const float* Wv = (const float*)d_in[3];
    const float* bv = (const float*)d_in[4];
    const float* Wo = (const float*)d_in[5];
    const float* bo = (const float*)d_in[6];
    float* out = (float*)d_out;

    char* ws = (char*)d_ws;
    bf16* Xb   = (bf16*)ws;                          // 16 MB (reused as AO after GEMM1)
    bf16* Wqvt = (bf16*)(ws + (size_t)(16 << 20));   // 4 MB
    bf16* Wot  = (bf16*)(ws + (size_t)(20 << 20));   // 2 MB
    bf16* Qb   = (bf16*)(ws + (size_t)(22 << 20));   // 16 MB
    bf16* Vtb  = (bf16*)(ws + (size_t)(38 << 20));   // 16 MB
    float* QN  = (float*)(ws + (size_t)(54 << 20));  // 0.5 MB
    bf16* AO   = Xb;                                 // reuse: Xb dead after GEMM1

    k_cast_x<<<8192, 256, 0, stream>>>((const float4*)x, (bf16x4*)Xb);
    dim3 tb(32, 8);
    k_transpose_cast<<<dim3(32, 32), tb, 0, stream>>>(Wq, Wqvt);
    k_transpose_cast<<<dim3(32, 32), tb, 0, stream>>>(Wv, Wqvt + 1024 * 1024);
    k_transpose_cast<<<dim3(32, 32), tb, 0, stream>>>(Wo, Wot);
    k_gemm_qv<<<dim3(16, 64), 256, 0, stream>>>(Xb, Wqvt, bq, bv, Qb, Vtb, QN);
    k_attn<<<dim3(32, 64), 256, 0, stream>>>(Qb, Vtb, QN, AO);
    k_gemm_out<<<dim3(8, 64), 256, 0, stream>>>(AO, Wot, bo, out);
}